// Round 1
// baseline (92.311 us; speedup 1.0000x reference)
//
#include <hip/hip_runtime.h>
#include <math.h>

// FSQ: x (64,32768,4) f32 -> z (level-major transposed layout) + code.
// LEVELS = [8,5,5,5], N rows of D=4.
//
// Two-kernel split: fsq_fast is a pure streaming kernel (no f64 anywhere,
// ~30 VGPR, full occupancy); rows whose fast-path value lands within
// GTHR of a quantization decision boundary (~1e-3 of rows) are pushed to a
// workspace list and re-done exactly (f64 tanh + exact argmin) by fsq_fix.

#define N_ROWS 2097152  // 64*32768

// Levels replicating np.linspace(-1,1,n,dtype=float32).
__device__ __constant__ float L8[8] = {
    -1.0f,
    (float)(1.0 * (2.0 / 7.0) - 1.0),
    (float)(2.0 * (2.0 / 7.0) - 1.0),
    (float)(3.0 * (2.0 / 7.0) - 1.0),
    (float)(4.0 * (2.0 / 7.0) - 1.0),
    (float)(5.0 * (2.0 / 7.0) - 1.0),
    (float)(6.0 * (2.0 / 7.0) - 1.0),
    1.0f};
__device__ __constant__ float L5[5] = {-1.0f, -0.5f, 0.0f, 0.5f, 1.0f};

// Exact slow-path quant: replicate np argmin |lv[j]-xi| (first-occurrence).
template <int NLEV>
__device__ inline int quant_exact(float xi, const float* __restrict__ lv) {
    float best = fabsf(lv[0] - xi);
    int bi = 0;
#pragma unroll
    for (int j = 1; j < NLEV; ++j) {
        float d = fabsf(lv[j] - xi);
        if (d < best) { best = d; bi = j; }
    }
    return bi;
}

// Fast tanh: t = 1 - 2*rcp(exp2(x*2/ln2) + 1).
// v_exp_f32 (~1 ulp) + v_rcp_f32 (~1 ulp) -> abs output error <= ~1e-6.
__device__ __forceinline__ float fast_tanh(float x) {
    float e = __builtin_amdgcn_exp2f(x * 2.88539008177792681472f);  // 2/ln2
    return fmaf(-2.0f, __builtin_amdgcn_rcpf(e + 1.0f), 1.0f);
}

// Guard: |v - rint(v)| > 0.5 - EPS_U  => too close to a decision boundary,
// defer to the exact fixup kernel. EPS_U = 5e-5 units vs fast-path error
// <= 3.5e-6 units (14x margin), so off-guard indices are provably identical
// to the reference. (Same guard as the previous verified-absmax-0 kernel.)
#define GTHR (0.5f - 5e-5f)

__global__ __launch_bounds__(256) void fsq_fast(
    const float4* __restrict__ x, float* __restrict__ out,
    int* __restrict__ cnt, int* __restrict__ list, int cap) {
    const int t = blockIdx.x * blockDim.x + threadIdx.x;  // grid == N_ROWS/256
    const float4 xv = x[t];

    const float t0 = fast_tanh(xv.x);
    const float t1 = fast_tanh(xv.y);
    const float t2 = fast_tanh(xv.z);
    const float t3 = fast_tanh(xv.w);

    // v = (t+1)*s ; k = rint(v) ; |v-k| = distance to decision boundary
    const float v0 = fmaf(t0, 3.5f, 3.5f);
    const float v1 = fmaf(t1, 2.0f, 2.0f);
    const float v2 = fmaf(t2, 2.0f, 2.0f);
    const float v3 = fmaf(t3, 2.0f, 2.0f);
    const float k0 = rintf(v0);
    const float k1 = rintf(v1);
    const float k2 = rintf(v2);
    const float k3 = rintf(v3);
    const float m = fmaxf(fmaxf(fabsf(v0 - k0), fabsf(v1 - k1)),
                          fmaxf(fabsf(v2 - k2), fabsf(v3 - k3)));

    // q values: dim0 bit-matches L8 via the same double formula;
    // dims 1-3 exact in f32. code = i0 + 8*i1 + 40*i2 + 200*i3 (<= 999,
    // exact in f32). Stores: 5 coalesced dword streams (256B/wave/instr).
    out[0 * N_ROWS + t] = (float)((double)k0 * (2.0 / 7.0) - 1.0);
    out[1 * N_ROWS + t] = fmaf(k1, 0.5f, -1.0f);
    out[2 * N_ROWS + t] = fmaf(k2, 0.5f, -1.0f);
    out[3 * N_ROWS + t] = fmaf(k3, 0.5f, -1.0f);
    out[4 * N_ROWS + t] = fmaf(200.0f, k3, fmaf(40.0f, k2, fmaf(8.0f, k1, k0)));

    if (m > GTHR) {
        const int i = atomicAdd(cnt, 1);
        if (i < cap) list[i] = t;
    }
}

// Exact fixup for boundary-adjacent rows. f64 tanh rounds to numpy's f32
// tanh (verified absmax 0.0 previously); exact first-occurrence argmin.
__global__ __launch_bounds__(256) void fsq_fix(
    const float4* __restrict__ x, float* __restrict__ out,
    const int* __restrict__ cnt, const int* __restrict__ list, int cap) {
    int n = *cnt;
    if (n > cap) n = cap;
    for (int i = blockIdx.x * blockDim.x + threadIdx.x; i < n;
         i += gridDim.x * blockDim.x) {
        const int t = list[i];
        const float4 xv = x[t];
        const float xi0 = (float)tanh((double)xv.x);
        const float xi1 = (float)tanh((double)xv.y);
        const float xi2 = (float)tanh((double)xv.z);
        const float xi3 = (float)tanh((double)xv.w);
        const int i0 = quant_exact<8>(xi0, L8);
        const int i1 = quant_exact<5>(xi1, L5);
        const int i2 = quant_exact<5>(xi2, L5);
        const int i3 = quant_exact<5>(xi3, L5);
        const float k1 = (float)i1, k2 = (float)i2, k3 = (float)i3;
        out[0 * N_ROWS + t] = (float)((double)i0 * (2.0 / 7.0) - 1.0);
        out[1 * N_ROWS + t] = fmaf(k1, 0.5f, -1.0f);
        out[2 * N_ROWS + t] = fmaf(k2, 0.5f, -1.0f);
        out[3 * N_ROWS + t] = fmaf(k3, 0.5f, -1.0f);
        out[4 * N_ROWS + t] =
            fmaf(200.0f, k3, fmaf(40.0f, k2, fmaf(8.0f, k1, (float)i0)));
    }
}

extern "C" void kernel_launch(void* const* d_in, const int* in_sizes, int n_in,
                              void* d_out, int out_size, void* d_ws, size_t ws_size,
                              hipStream_t stream) {
    const float4* x = (const float4*)d_in[0];
    float* out = (float*)d_out;
    int* cnt = (int*)d_ws;
    int* list = (int*)((char*)d_ws + 16);
    long long capll = ws_size > 16 ? (long long)((ws_size - 16) / 4) : 0;
    int cap = capll > N_ROWS ? N_ROWS : (int)capll;

    hipMemsetAsync(d_ws, 0, 4, stream);  // zero suspect counter (ws is poisoned)
    fsq_fast<<<N_ROWS / 256, 256, 0, stream>>>(x, out, cnt, list, cap);
    fsq_fix<<<16, 256, 0, stream>>>(x, out, cnt, list, cap);
}

// Round 3
// 86.470 us; speedup vs baseline: 1.0675x; 1.0675x over previous
//
#include <hip/hip_runtime.h>
#include <math.h>

// FSQ: x (64,32768,4) f32 -> z (level-major transposed layout) + code.
// LEVELS = [8,5,5,5], N rows of D=4.
//
// Single fused dispatch. Post-mortem of the two-kernel split (R1): dur_us
// 87.0 -> 92.3, i.e. the split only added launch overhead. The fused kernel
// is already at its traffic floor (~75.5 MB => ~12 us @ 6.3 TB/s); the rest
// of dur_us is fixed harness re-poison cost (256 MiB ws fill = 43.5 us +
// tiny restore dispatches). So: one kernel, no workspace, no extra launches.
// (R2 bench was an infra failure — container acquire — not a kernel issue;
// this is the verified absmax-0.0 source resubmitted.)
#define N_ROWS 2097152  // 64*32768
#define NPT 4           // rows per thread (float4-coalesced stores need 4)

// Levels replicating np.linspace(-1,1,n,dtype=float32).
__device__ __constant__ float L8[8] = {
    -1.0f,
    (float)(1.0 * (2.0 / 7.0) - 1.0),
    (float)(2.0 * (2.0 / 7.0) - 1.0),
    (float)(3.0 * (2.0 / 7.0) - 1.0),
    (float)(4.0 * (2.0 / 7.0) - 1.0),
    (float)(5.0 * (2.0 / 7.0) - 1.0),
    (float)(6.0 * (2.0 / 7.0) - 1.0),
    1.0f};
__device__ __constant__ float L5[5] = {-1.0f, -0.5f, 0.0f, 0.5f, 1.0f};

// Exact slow-path quant: replicate np argmin |lv[j]-xi| (first-occurrence).
template <int NLEV>
__device__ inline void quant_exact(float xi, const float* __restrict__ lv,
                                   int& idx) {
    float best = fabsf(lv[0] - xi);
    int bi = 0;
#pragma unroll
    for (int j = 1; j < NLEV; ++j) {
        float d = fabsf(lv[j] - xi);
        if (d < best) { best = d; bi = j; }
    }
    idx = bi;
}

// Fast tanh: t = 1 - 2*rcp(exp2(x*2/ln2) + 1).
// v_exp_f32 (~1 ulp) + v_rcp_f32 (~1 ulp) -> abs output error <= ~1e-6.
__device__ __forceinline__ float fast_tanh(float x) {
    float e = __builtin_amdgcn_exp2f(x * 2.88539008177792681472f);  // 2/ln2
    return fmaf(-2.0f, __builtin_amdgcn_rcpf(e + 1.0f), 1.0f);
}

// Guard: |v - rint(v)| > 0.5 - EPS_U  => too close to a decision boundary,
// take the exact path. EPS_U = 5e-5 units vs fast-path error <= 3.5e-6 units
// (14x margin), so off-guard indices are provably identical to the reference.
#define GTHR (0.5f - 5e-5f)

__global__ __launch_bounds__(256) void fsq_kernel(const float* __restrict__ x,
                                                  float* __restrict__ out) {
    const int t = blockIdx.x * blockDim.x + threadIdx.x;
    if (t >= N_ROWS / NPT) return;
    const long long n0 = (long long)t * NPT;

    float z0[NPT], z1[NPT], z2[NPT], z3[NPT], cf[NPT];
    float4 xin[NPT];

#pragma unroll
    for (int j = 0; j < NPT; ++j)
        xin[j] = reinterpret_cast<const float4*>(x)[n0 + j];

#pragma unroll
    for (int j = 0; j < NPT; ++j) {
        const float4 xv = xin[j];
        float t0 = fast_tanh(xv.x);
        float t1 = fast_tanh(xv.y);
        float t2 = fast_tanh(xv.z);
        float t3 = fast_tanh(xv.w);

        // v = (t+1)*s ; k = rint(v) ; d = v-k (boundary distance)
        float v0 = fmaf(t0, 3.5f, 3.5f);
        float v1 = fmaf(t1, 2.0f, 2.0f);
        float v2 = fmaf(t2, 2.0f, 2.0f);
        float v3 = fmaf(t3, 2.0f, 2.0f);
        float k0 = rintf(v0);
        float k1 = rintf(v1);
        float k2 = rintf(v2);
        float k3 = rintf(v3);
        float m = fmaxf(fmaxf(fabsf(v0 - k0), fabsf(v1 - k1)),
                        fmaxf(fabsf(v2 - k2), fabsf(v3 - k3)));

        if (m > GTHR) {
            // Exact reference path: f64 tanh (rounds to numpy f32 tanh,
            // verified absmax 0.0) + exact argmin with f32 levels.
            float xi0 = (float)tanh((double)xv.x);
            float xi1 = (float)tanh((double)xv.y);
            float xi2 = (float)tanh((double)xv.z);
            float xi3 = (float)tanh((double)xv.w);
            int i0, i1, i2, i3;
            quant_exact<8>(xi0, L8, i0);
            quant_exact<5>(xi1, L5, i1);
            quant_exact<5>(xi2, L5, i2);
            quant_exact<5>(xi3, L5, i3);
            k0 = (float)i0; k1 = (float)i1; k2 = (float)i2; k3 = (float)i3;
        }

        // q values: dim0 bit-matches L8 via the same double formula;
        // dims 1-3 exact in f32. (st = xi + (q - xi) == q exactly here is
        // within 1 ulp of the reference's f32 st.)
        z0[j] = (float)((double)k0 * (2.0 / 7.0) - 1.0);
        z1[j] = fmaf(k1, 0.5f, -1.0f);
        z2[j] = fmaf(k2, 0.5f, -1.0f);
        z3[j] = fmaf(k3, 0.5f, -1.0f);
        // code = i0 + 8*i1 + 40*i2 + 200*i3 (integers <= 999, exact in f32)
        cf[j] = fmaf(200.0f, k3, fmaf(40.0f, k2, fmaf(8.0f, k1, k0)));
    }

    float4* o0 = reinterpret_cast<float4*>(out + 0ll * N_ROWS);
    float4* o1 = reinterpret_cast<float4*>(out + 1ll * N_ROWS);
    float4* o2 = reinterpret_cast<float4*>(out + 2ll * N_ROWS);
    float4* o3 = reinterpret_cast<float4*>(out + 3ll * N_ROWS);
    float4* oc = reinterpret_cast<float4*>(out + 4ll * N_ROWS);
    o0[t] = make_float4(z0[0], z0[1], z0[2], z0[3]);
    o1[t] = make_float4(z1[0], z1[1], z1[2], z1[3]);
    o2[t] = make_float4(z2[0], z2[1], z2[2], z2[3]);
    o3[t] = make_float4(z3[0], z3[1], z3[2], z3[3]);
    oc[t] = make_float4(cf[0], cf[1], cf[2], cf[3]);
}

extern "C" void kernel_launch(void* const* d_in, const int* in_sizes, int n_in,
                              void* d_out, int out_size, void* d_ws, size_t ws_size,
                              hipStream_t stream) {
    const float* x = (const float*)d_in[0];
    float* out = (float*)d_out;
    const int threads = 256;
    const int total = N_ROWS / NPT;
    const int blocks = (total + threads - 1) / threads;
    fsq_kernel<<<blocks, threads, 0, stream>>>(x, out);
}